// Round 5
// baseline (497.701 us; speedup 1.0000x reference)
//
#include <hip/hip_runtime.h>

typedef _Float16 f16;
typedef _Float16 f16x8 __attribute__((ext_vector_type(8)));
typedef float f32x4 __attribute__((ext_vector_type(4)));

#define N_ATOMS 50000
#define NEIGH   12
#define NEDGE   (N_ATOMS * NEIGH)
#define NCRYS   500
#define NBLK    196  // ceil(50000/256)

__device__ __forceinline__ void gld_lds16(const void* g, void* l) {
  __builtin_amdgcn_global_load_lds(
      (const __attribute__((address_space(1))) unsigned int*)g,
      (__attribute__((address_space(3))) unsigned int*)l, 16, 0, 0);
}

// ---------------- layer-1 GEMM: P = GBF(A)@Wl^T, Q = GBF(A)@Wr^T ----------------
// Wcat fp16 [256][K] (rows 0-127 = Wl, 128-255 = Wr). BM=64, BN=256, 8 waves.
// MODE 1: bond fp32 [N][12], GBF K=480 (40 filters, gamma=0.2)
// MODE 2: angle fp32 [N][144], GBF K=1152 (8 filters, gamma=0.25)
template <int MODE, int K>
__global__ __launch_bounds__(512) void gemm1(
    const float* __restrict__ Asrc, const f16* __restrict__ Wcat,
    f16* __restrict__ P, f16* __restrict__ Q, int n) {
  __shared__ __align__(16) f16 As[2][4][64][8];   // 8 KB
  __shared__ __align__(16) f16 Bs[2][4][256][8];  // 32 KB
  const int tid = threadIdx.x;
  const int lane = tid & 63;
  const int wid = tid >> 6;
  const int wr = wid >> 2;  // 0..1 (32-row strip)
  const int wc = wid & 3;   // 0..3 (64-col strip)
  const int row0 = blockIdx.x * 64;

  const int sBcol = tid & 255;
  const int sBkb = tid >> 8;  // 0..1
  const int sArow = tid & 63;
  const int sAkb = (tid >> 6) & 3;
  int arow = row0 + sArow;
  if (arow >= n) arow = n - 1;

  f32x4 acc[2][4];
#pragma unroll
  for (int m = 0; m < 2; ++m)
#pragma unroll
    for (int q = 0; q < 4; ++q) acc[m][q] = (f32x4)0.f;

  auto stage = [&](int buf, int k0) {
#pragma unroll
    for (int p = 0; p < 2; ++p) {
      int kb = sBkb + 2 * p;
      gld_lds16(Wcat + (size_t)sBcol * K + k0 + kb * 8, &Bs[buf][kb][sBcol][0]);
    }
    if (tid < 256) {
      int kg0 = k0 + sAkb * 8;
      f16 v[8];
      if constexpr (MODE == 1) {
        int jn = kg0 / 40;            // 40 % 8 == 0: an 8-block never crosses a filter group
        int kk0 = kg0 - jn * 40;
        float d = Asrc[arow * NEIGH + jn];
#pragma unroll
        for (int j = 0; j < 8; ++j) {
          float t = d - (kk0 + j) * (8.0f / 39.0f);
          v[j] = (f16)__expf(-t * t * 25.0f);
        }
      } else {
        int jn = kg0 >> 3;
        float d = Asrc[arow * 144 + jn];
#pragma unroll
        for (int j = 0; j < 8; ++j) {
          float t = d - (-1.0f + j * (2.0f / 7.0f));
          v[j] = (f16)__expf(-t * t * 16.0f);
        }
      }
      *(f16x8*)&As[buf][sAkb][sArow][0] = *(const f16x8*)v;
    }
  };

  constexpr int NT = K / 32;
  stage(0, 0);
  __syncthreads();
  int buf = 0;
  for (int t = 0; t < NT; ++t) {
    if (t + 1 < NT) stage(buf ^ 1, (t + 1) * 32);
    const int kb = lane >> 4;
    const int r16 = lane & 15;
    f16x8 a[2], b[4];
#pragma unroll
    for (int m = 0; m < 2; ++m)
      a[m] = *(const f16x8*)&As[buf][kb][wr * 32 + m * 16 + r16][0];
#pragma unroll
    for (int q = 0; q < 4; ++q)
      b[q] = *(const f16x8*)&Bs[buf][kb][wc * 64 + q * 16 + r16][0];
#pragma unroll
    for (int m = 0; m < 2; ++m)
#pragma unroll
      for (int q = 0; q < 4; ++q)
        acc[m][q] =
            __builtin_amdgcn_mfma_f32_16x16x32_f16(a[m], b[q], acc[m][q], 0, 0, 0);
    __syncthreads();
    buf ^= 1;
  }

  const int crow = (lane >> 4) * 4;
  const int ccol = lane & 15;
  f16* baseo = (wc < 2) ? P : Q;
  const int cbase = (wc & 1) * 64;
#pragma unroll
  for (int m = 0; m < 2; ++m) {
#pragma unroll
    for (int r = 0; r < 4; ++r) {
      int row = row0 + wr * 32 + m * 16 + crow + r;
      if (row < n) {
#pragma unroll
        for (int q = 0; q < 4; ++q)
          baseo[(size_t)row * 128 + cbase + q * 16 + ccol] = (f16)acc[m][q][r];
      }
    }
  }
}

// ---------------- layers 2-3: x' = relu([agg|x] @ Wcat2^T + b) ----------------
// axcat [N][256]: cols 0-127 = agg, 128-255 = x (in-place update of x half).
// Wcat2 [128][256]: k<128 -> Wl[c][k], k>=128 -> Wr[c][k-128]. blockIdx.y = path.
__global__ __launch_bounds__(256) void gemmL(
    f16* __restrict__ axb, f16* __restrict__ axa, const f16* __restrict__ Wall,
    const float* __restrict__ bb, const float* __restrict__ ba, int lidx, int n) {
  __shared__ __align__(16) f16 As[2][4][64][8];   // 8 KB
  __shared__ __align__(16) f16 Bs[2][4][128][8];  // 16 KB
  const int path = blockIdx.y;
  f16* ax = path ? axa : axb;
  const f16* W = Wall + (size_t)(path * 2 + lidx) * 32768;
  const float* bias = (path ? ba : bb) + lidx * 128;

  const int tid = threadIdx.x;
  const int lane = tid & 63;
  const int wid = tid >> 6;  // 0..3
  const int wr = wid >> 1;   // 0..1 (32-row strip)
  const int wc = wid & 1;    // 0..1 (64-col strip)
  const int row0 = blockIdx.x * 64;

  const int sArow = tid & 63;
  const int sAkb = tid >> 6;  // 0..3
  int arow = row0 + sArow;
  if (arow >= n) arow = n - 1;

  f32x4 acc[2][4];
#pragma unroll
  for (int m = 0; m < 2; ++m)
#pragma unroll
    for (int q = 0; q < 4; ++q) acc[m][q] = (f32x4)0.f;

  auto stage = [&](int buf, int k0) {
#pragma unroll
    for (int p = 0; p < 2; ++p) {
      int u = p * 4 + wid;
      int kb = u & 3;
      int c = (u >> 2) * 64 + lane;
      gld_lds16(W + (size_t)c * 256 + k0 + kb * 8, &Bs[buf][kb][c][0]);
    }
    gld_lds16(ax + (size_t)arow * 256 + k0 + sAkb * 8, &As[buf][sAkb][sArow][0]);
  };

  stage(0, 0);
  __syncthreads();
  int buf = 0;
  for (int t = 0; t < 8; ++t) {
    if (t + 1 < 8) stage(buf ^ 1, (t + 1) * 32);
    const int kb = lane >> 4;
    const int r16 = lane & 15;
    f16x8 a[2], b[4];
#pragma unroll
    for (int m = 0; m < 2; ++m)
      a[m] = *(const f16x8*)&As[buf][kb][wr * 32 + m * 16 + r16][0];
#pragma unroll
    for (int q = 0; q < 4; ++q)
      b[q] = *(const f16x8*)&Bs[buf][kb][wc * 64 + q * 16 + r16][0];
#pragma unroll
    for (int m = 0; m < 2; ++m)
#pragma unroll
      for (int q = 0; q < 4; ++q)
        acc[m][q] =
            __builtin_amdgcn_mfma_f32_16x16x32_f16(a[m], b[q], acc[m][q], 0, 0, 0);
    __syncthreads();
    buf ^= 1;
  }

  const int crow = (lane >> 4) * 4;
  const int ccol = lane & 15;
#pragma unroll
  for (int m = 0; m < 2; ++m) {
#pragma unroll
    for (int r = 0; r < 4; ++r) {
      int row = row0 + wr * 32 + m * 16 + crow + r;
      if (row < n) {
#pragma unroll
        for (int q = 0; q < 4; ++q) {
          int col = wc * 64 + q * 16 + ccol;
          float v = acc[m][q][r] + bias[col];
          ax[(size_t)row * 256 + 128 + col] = (f16)fmaxf(v, 0.0f);
        }
      }
    }
  }
}

// ---------------- weight conversion ----------------
__global__ void cvtW(const float* __restrict__ Wl, const float* __restrict__ Wr,
                     f16* __restrict__ outp, int K) {
  int c = blockIdx.y;
  int k = blockIdx.x * 256 + threadIdx.x;
  if (k < K)
    outp[(size_t)c * K + k] =
        (f16)((c < 128) ? Wl[(size_t)c * K + k] : Wr[(size_t)(c - 128) * K + k]);
}

// [4][128][256]: l = {b0,b1,a0,a1}; k<128 -> Wl, k>=128 -> Wr
__global__ void cvtW_small(const float* __restrict__ Wl_b, const float* __restrict__ Wr_b,
                           const float* __restrict__ Wl_a, const float* __restrict__ Wr_a,
                           f16* __restrict__ outp) {
  int idx = blockIdx.x * 256 + threadIdx.x;  // 4*128*256 = 131072
  int l = idx >> 15;
  int c = (idx >> 8) & 127;
  int k = idx & 255;
  const float* Wl = (l < 2) ? Wl_b + (size_t)l * 16384 : Wl_a + (size_t)(l - 2) * 16384;
  const float* Wr = (l < 2) ? Wr_b + (size_t)l * 16384 : Wr_a + (size_t)(l - 2) * 16384;
  float v = (k < 128) ? Wl[(size_t)c * 128 + k] : Wr[(size_t)c * 128 + (k - 128)];
  outp[idx] = (f16)v;
}

// ---------------- CSR build ----------------
__global__ void k_count(const int* __restrict__ nbr, int* __restrict__ deg) {
  int e = blockIdx.x * 256 + threadIdx.x;
  if (e < NEDGE) atomicAdd(&deg[nbr[e]], 1);
}
__global__ void k_scan1(const int* __restrict__ deg, int* __restrict__ rowptr,
                        int* __restrict__ bsum) {
  __shared__ int s[256];
  int t = threadIdx.x, i = blockIdx.x * 256 + t;
  int v = (i < N_ATOMS) ? deg[i] : 0;
  s[t] = v;
  __syncthreads();
  for (int off = 1; off < 256; off <<= 1) {
    int x = (t >= off) ? s[t - off] : 0;
    __syncthreads();
    s[t] += x;
    __syncthreads();
  }
  if (i < N_ATOMS) rowptr[i] = s[t] - v;
  if (t == 255) bsum[blockIdx.x] = s[255];
}
__global__ void k_scan2(int* __restrict__ bsum) {
  __shared__ int s[256];
  int t = threadIdx.x;
  int v = (t < NBLK) ? bsum[t] : 0;
  s[t] = v;
  __syncthreads();
  for (int off = 1; off < 256; off <<= 1) {
    int x = (t >= off) ? s[t - off] : 0;
    __syncthreads();
    s[t] += x;
    __syncthreads();
  }
  if (t < NBLK) bsum[t] = s[t] - v;
}
__global__ void k_scan3(int* __restrict__ rowptr, const int* __restrict__ bsum) {
  int i = blockIdx.x * 256 + threadIdx.x;
  if (i < N_ATOMS) rowptr[i] += bsum[blockIdx.x];
  if (i == 0) rowptr[N_ATOMS] = NEDGE;
}
__global__ void k_fill(const int* __restrict__ nbr, const int* __restrict__ rowptr,
                       int* __restrict__ cursor, int* __restrict__ eidx) {
  int e = blockIdx.x * 256 + threadIdx.x;
  if (e < NEDGE) {
    int dst = nbr[e];
    int pos = rowptr[dst] + atomicAdd(&cursor[dst], 1);
    eidx[pos] = e / NEIGH;
  }
}

// ---------------- layer-1 finalize: x = relu(mean_j P[src_j] + b + Q) ----------------
// grid (N/16, 2); writes x half of axcat. 16 threads/atom, f16x8 per edge.
__global__ __launch_bounds__(256) void gather_fin1(
    const f16* __restrict__ Pb, const f16* __restrict__ Qb,
    const f16* __restrict__ Pa, const f16* __restrict__ Qa,
    const int* __restrict__ rowptr, const int* __restrict__ eidx,
    const float* __restrict__ bias_b, const float* __restrict__ bias_a,
    f16* __restrict__ axb, f16* __restrict__ axa) {
  const int path = blockIdx.y;
  const f16* P = path ? Pa : Pb;
  const f16* Q = path ? Qa : Qb;
  const float* bias = path ? bias_a : bias_b;
  f16* ax = path ? axa : axb;
  const int t = threadIdx.x;
  const int a = blockIdx.x * 16 + (t >> 4);
  const int g = (t & 15) * 8;
  const int s0 = rowptr[a], s1 = rowptr[a + 1];
  float acc[8];
#pragma unroll
  for (int u = 0; u < 8; ++u) acc[u] = 0.f;
  int j = s0;
  for (; j + 4 <= s1; j += 4) {
    int src0 = eidx[j], src1 = eidx[j + 1], src2 = eidx[j + 2], src3 = eidx[j + 3];
    f16x8 v0 = *(const f16x8*)&P[(size_t)src0 * 128 + g];
    f16x8 v1 = *(const f16x8*)&P[(size_t)src1 * 128 + g];
    f16x8 v2 = *(const f16x8*)&P[(size_t)src2 * 128 + g];
    f16x8 v3 = *(const f16x8*)&P[(size_t)src3 * 128 + g];
#pragma unroll
    for (int u = 0; u < 8; ++u)
      acc[u] += ((float)v0[u] + (float)v1[u]) + ((float)v2[u] + (float)v3[u]);
  }
  for (; j < s1; ++j) {
    f16x8 v = *(const f16x8*)&P[(size_t)eidx[j] * 128 + g];
#pragma unroll
    for (int u = 0; u < 8; ++u) acc[u] += (float)v[u];
  }
  f16x8 q = *(const f16x8*)&Q[(size_t)a * 128 + g];
  float inv = 1.0f / fmaxf((float)(s1 - s0), 1.0f);
  f16 outv[8];
#pragma unroll
  for (int u = 0; u < 8; ++u) {
    float v = acc[u] * inv + bias[g + u] + (float)q[u];
    outv[u] = (f16)fmaxf(v, 0.0f);
  }
  *(f16x8*)&ax[(size_t)a * 256 + 128 + g] = *(const f16x8*)outv;
}

// ---------------- layers 2-3 aggregation: agg half <- mean_j x[src_j] ----------------
__global__ __launch_bounds__(256) void gather_mean(
    f16* __restrict__ axb, f16* __restrict__ axa,
    const int* __restrict__ rowptr, const int* __restrict__ eidx) {
  f16* ax = blockIdx.y ? axa : axb;
  const int t = threadIdx.x;
  const int a = blockIdx.x * 16 + (t >> 4);
  const int g = (t & 15) * 8;
  const int s0 = rowptr[a], s1 = rowptr[a + 1];
  float acc[8];
#pragma unroll
  for (int u = 0; u < 8; ++u) acc[u] = 0.f;
  int j = s0;
  for (; j + 4 <= s1; j += 4) {
    int src0 = eidx[j], src1 = eidx[j + 1], src2 = eidx[j + 2], src3 = eidx[j + 3];
    f16x8 v0 = *(const f16x8*)&ax[(size_t)src0 * 256 + 128 + g];
    f16x8 v1 = *(const f16x8*)&ax[(size_t)src1 * 256 + 128 + g];
    f16x8 v2 = *(const f16x8*)&ax[(size_t)src2 * 256 + 128 + g];
    f16x8 v3 = *(const f16x8*)&ax[(size_t)src3 * 256 + 128 + g];
#pragma unroll
    for (int u = 0; u < 8; ++u)
      acc[u] += ((float)v0[u] + (float)v1[u]) + ((float)v2[u] + (float)v3[u]);
  }
  for (; j < s1; ++j) {
    f16x8 v = *(const f16x8*)&ax[(size_t)eidx[j] * 256 + 128 + g];
#pragma unroll
    for (int u = 0; u < 8; ++u) acc[u] += (float)v[u];
  }
  float inv = 1.0f / fmaxf((float)(s1 - s0), 1.0f);
  f16 outv[8];
#pragma unroll
  for (int u = 0; u < 8; ++u) outv[u] = (f16)(acc[u] * inv);
  *(f16x8*)&ax[(size_t)a * 256 + g] = *(const f16x8*)outv;
}

// ---------------- head: pool -> mlp -> mlp -> fc ----------------
__global__ __launch_bounds__(256) void head_kernel(
    const f16* __restrict__ axb, const f16* __restrict__ axa,
    const int* __restrict__ crys, const float* __restrict__ W_mlp,
    const float* __restrict__ b_mlp, const float* __restrict__ W_fc,
    const float* __restrict__ b_fc, float* __restrict__ outp) {
  __shared__ float sh0[256], sh1[256];
  const int cry = blockIdx.x, c = threadIdx.x;
  const int s = crys[2 * cry], e = crys[2 * cry + 1];
  const f16* src = (c < 128) ? axb : axa;
  const int ch = c & 127;
  float sum = 0.f;
  for (int r = s; r < e; ++r) sum += (float)src[(size_t)r * 256 + 128 + ch];
  sh0[c] = sum / fmaxf((float)(e - s), 1.0f);
  __syncthreads();
  {
    const float* wrow = W_mlp + (size_t)c * 256;
    float s2 = b_mlp[c];
#pragma unroll 8
    for (int k = 0; k < 256; k += 4) {
      float4 w = *(const float4*)&wrow[k];
      s2 += sh0[k] * w.x + sh0[k + 1] * w.y + sh0[k + 2] * w.z + sh0[k + 3] * w.w;
    }
    sh1[c] = s2;
  }
  __syncthreads();
  {
    const float* wrow = W_mlp + 65536 + (size_t)c * 256;
    float s2 = b_mlp[256 + c];
#pragma unroll 8
    for (int k = 0; k < 256; k += 4) {
      float4 w = *(const float4*)&wrow[k];
      s2 += sh1[k] * w.x + sh1[k + 1] * w.y + sh1[k + 2] * w.z + sh1[k + 3] * w.w;
    }
    sh0[c] = s2;
  }
  __syncthreads();
  if (c < 2) {
    const float* wrow = W_fc + c * 256;
    float s2 = b_fc[c];
    for (int k = 0; k < 256; ++k) s2 += sh0[k] * wrow[k];
    outp[cry * 2 + c] = s2;
  }
}

extern "C" void kernel_launch(void* const* d_in, const int* in_sizes, int n_in,
                              void* d_out, int out_size, void* d_ws, size_t ws_size,
                              hipStream_t stream) {
  const float* bond  = (const float*)d_in[0];
  const float* angle = (const float*)d_in[1];
  const int*   nbr   = (const int*)d_in[3];
  const int*   crys  = (const int*)d_in[4];
  const float* Wl_b1 = (const float*)d_in[5];
  const float* Wr_b1 = (const float*)d_in[6];
  const float* b_b1  = (const float*)d_in[7];
  const float* Wl_a1 = (const float*)d_in[8];
  const float* Wr_a1 = (const float*)d_in[9];
  const float* b_a1  = (const float*)d_in[10];
  const float* Wl_b  = (const float*)d_in[11];
  const float* Wr_b  = (const float*)d_in[12];
  const float* b_b   = (const float*)d_in[13];
  const float* Wl_a  = (const float*)d_in[14];
  const float* Wr_a  = (const float*)d_in[15];
  const float* b_a   = (const float*)d_in[16];
  const float* W_mlp = (const float*)d_in[17];
  const float* b_mlp = (const float*)d_in[18];
  const float* W_fc  = (const float*)d_in[19];
  const float* b_fc  = (const float*)d_in[20];

  char* w = (char*)d_ws;
  auto alloc = [&](size_t bytes) {
    void* p = (void*)w;
    w += (bytes + 255) & ~(size_t)255;
    return p;
  };
  f16* Pb   = (f16*)alloc((size_t)N_ATOMS * 128 * 2);
  f16* Qb   = (f16*)alloc((size_t)N_ATOMS * 128 * 2);
  f16* Pa   = (f16*)alloc((size_t)N_ATOMS * 128 * 2);
  f16* Qa   = (f16*)alloc((size_t)N_ATOMS * 128 * 2);
  f16* axb  = (f16*)alloc((size_t)N_ATOMS * 256 * 2);
  f16* axa  = (f16*)alloc((size_t)N_ATOMS * 256 * 2);
  f16* Wb1c = (f16*)alloc((size_t)256 * 480 * 2);
  f16* Wa1c = (f16*)alloc((size_t)256 * 1152 * 2);
  f16* Wsm  = (f16*)alloc((size_t)4 * 128 * 256 * 2);
  // deg+cursor as ONE contiguous block: the single memset below must cover
  // BOTH (0xAA re-poison between timed replays otherwise leaves cursor garbage
  // -> OOB eidx writes on replay).
  int* deg    = (int*)alloc((size_t)2 * N_ATOMS * 4);
  int* cursor = deg + N_ATOMS;
  int* rowptr = (int*)alloc((size_t)(N_ATOMS + 1) * 4);
  int* eidx   = (int*)alloc((size_t)NEDGE * 4);
  int* bsum   = (int*)alloc(256 * 4);

  // weights -> fp16
  cvtW<<<dim3(2, 256), 256, 0, stream>>>(Wl_b1, Wr_b1, Wb1c, 480);
  cvtW<<<dim3(5, 256), 256, 0, stream>>>(Wl_a1, Wr_a1, Wa1c, 1152);
  cvtW_small<<<512, 256, 0, stream>>>(Wl_b, Wr_b, Wl_a, Wr_a, Wsm);

  // CSR build
  hipMemsetAsync(deg, 0, (size_t)2 * N_ATOMS * 4, stream);
  k_count<<<(NEDGE + 255) / 256, 256, 0, stream>>>(nbr, deg);
  k_scan1<<<NBLK, 256, 0, stream>>>(deg, rowptr, bsum);
  k_scan2<<<1, 256, 0, stream>>>(bsum);
  k_scan3<<<NBLK, 256, 0, stream>>>(rowptr, bsum);
  k_fill<<<(NEDGE + 255) / 256, 256, 0, stream>>>(nbr, rowptr, cursor, eidx);

  const int GG = (N_ATOMS + 63) / 64;  // 782
  const int AG = N_ATOMS / 16;         // 3125

  // layer 1 (project-then-aggregate; GBF fused into A staging)
  gemm1<1, 480><<<GG, 512, 0, stream>>>(bond, Wb1c, Pb, Qb, N_ATOMS);
  gemm1<2, 1152><<<GG, 512, 0, stream>>>(angle, Wa1c, Pa, Qa, N_ATOMS);
  gather_fin1<<<dim3(AG, 2), 256, 0, stream>>>(Pb, Qb, Pa, Qa, rowptr, eidx,
                                               b_b1, b_a1, axb, axa);

  // layers 2-3 (aggregate-then-project, both paths per launch)
  for (int l = 0; l < 2; ++l) {
    gather_mean<<<dim3(AG, 2), 256, 0, stream>>>(axb, axa, rowptr, eidx);
    gemmL<<<dim3(GG, 2), 256, 0, stream>>>(axb, axa, Wsm, b_b, b_a, l, N_ATOMS);
  }

  // head
  head_kernel<<<NCRYS, 256, 0, stream>>>(axb, axa, crys, W_mlp, b_mlp, W_fc, b_fc,
                                         (float*)d_out);
}

// Round 6
// 418.082 us; speedup vs baseline: 1.1904x; 1.1904x over previous
//
#include <hip/hip_runtime.h>

typedef _Float16 f16;
typedef _Float16 f16x8 __attribute__((ext_vector_type(8)));
typedef float f32x4 __attribute__((ext_vector_type(4)));

#define N_ATOMS 50000
#define NEIGH   12
#define NEDGE   (N_ATOMS * NEIGH)
#define NCRYS   500
#define NBLK    196  // ceil(50000/256)

__device__ __forceinline__ void gld_lds16(const void* g, void* l) {
  __builtin_amdgcn_global_load_lds(
      (const __attribute__((address_space(1))) unsigned int*)g,
      (__attribute__((address_space(3))) unsigned int*)l, 16, 0, 0);
}

// ---------------- layer-1 GEMM: out = GBF(A) @ Whalf^T ----------------
// BM=256 rows/block, BN=128 cols; blockIdx.y: 0 -> Wl half (P), 1 -> Wr half (Q).
// Rationale: time ~ staged-B bytes (~11 GB/s/CU gld_lds); BM=256 halves
// B-restaging vs BM=128 while keeping 392 blocks (>=256 CUs filled).
// MODE 1: bond fp32 [N][12], GBF K=480 (40 filters).
// MODE 2: angle fp32 [N][144], GBF K=1152 (8 filters).
template <int MODE, int K>
__global__ __launch_bounds__(512) void gemm1(
    const float* __restrict__ Asrc, const f16* __restrict__ Wcat,
    f16* __restrict__ P, f16* __restrict__ Q, int n) {
  __shared__ __align__(16) f16 As[2][4][256][8];  // 32 KB
  __shared__ __align__(16) f16 Bs[2][4][128][8];  // 16 KB
  const int tid = threadIdx.x;
  const int lane = tid & 63;
  const int wid = tid >> 6;
  const int wr = wid >> 1;  // 0..3 (64-row strip)
  const int wc = wid & 1;   // 0..1 (64-col strip)
  const int row0 = blockIdx.x * 256;
  const int half = blockIdx.y;
  const f16* Wh = Wcat + (size_t)half * 128 * K;
  f16* outp = half ? Q : P;

  const int bcol = tid & 127;
  const int bkb = tid >> 7;  // 0..3
  const int sArow = tid & 255;
  const int sAkb0 = tid >> 8;  // 0..1 (+2 on pass 1)
  int arow = row0 + sArow;
  if (arow >= n) arow = n - 1;

  f32x4 acc[4][4];
#pragma unroll
  for (int m = 0; m < 4; ++m)
#pragma unroll
    for (int q = 0; q < 4; ++q) acc[m][q] = (f32x4)0.f;

  auto stage = [&](int buf, int k0) {
    gld_lds16(Wh + (size_t)bcol * K + k0 + bkb * 8, &Bs[buf][bkb][bcol][0]);
#pragma unroll
    for (int p = 0; p < 2; ++p) {
      int kb = sAkb0 + 2 * p;
      int kg0 = k0 + kb * 8;
      f16 v[8];
      if constexpr (MODE == 1) {
        int jn = kg0 / 40;  // 40 % 8 == 0: 8-block never crosses a filter group
        int kk0 = kg0 - jn * 40;
        float d = Asrc[arow * NEIGH + jn];
#pragma unroll
        for (int j = 0; j < 8; ++j) {
          float t = d - (kk0 + j) * (8.0f / 39.0f);
          v[j] = (f16)__expf(-t * t * 25.0f);  // gamma = 8/40
        }
      } else {
        int jn = kg0 >> 3;
        float d = Asrc[arow * 144 + jn];
#pragma unroll
        for (int j = 0; j < 8; ++j) {
          float t = d - (-1.0f + j * (2.0f / 7.0f));
          v[j] = (f16)__expf(-t * t * 16.0f);  // gamma = 2/8
        }
      }
      *(f16x8*)&As[buf][kb][sArow][0] = *(const f16x8*)v;
    }
  };

  constexpr int NT = K / 32;
  stage(0, 0);
  __syncthreads();
  int buf = 0;
  for (int t = 0; t < NT; ++t) {
    if (t + 1 < NT) stage(buf ^ 1, (t + 1) * 32);
    const int kb = lane >> 4;
    const int r16 = lane & 15;
    f16x8 a[4], b[4];
#pragma unroll
    for (int m = 0; m < 4; ++m)
      a[m] = *(const f16x8*)&As[buf][kb][wr * 64 + m * 16 + r16][0];
#pragma unroll
    for (int q = 0; q < 4; ++q)
      b[q] = *(const f16x8*)&Bs[buf][kb][wc * 64 + q * 16 + r16][0];
#pragma unroll
    for (int m = 0; m < 4; ++m)
#pragma unroll
      for (int q = 0; q < 4; ++q)
        acc[m][q] =
            __builtin_amdgcn_mfma_f32_16x16x32_f16(a[m], b[q], acc[m][q], 0, 0, 0);
    __syncthreads();
    buf ^= 1;
  }

  const int crow = (lane >> 4) * 4;
  const int ccol = lane & 15;
#pragma unroll
  for (int m = 0; m < 4; ++m) {
#pragma unroll
    for (int r = 0; r < 4; ++r) {
      int row = row0 + wr * 64 + m * 16 + crow + r;
      if (row < n) {
#pragma unroll
        for (int q = 0; q < 4; ++q)
          outp[(size_t)row * 128 + wc * 64 + q * 16 + ccol] = (f16)acc[m][q][r];
      }
    }
  }
}

// ---------------- layers 2-3: x' = relu([agg|x] @ Wcat2^T + b) ----------------
// BM=256, BN=128, 512 threads. axcat [N][256]: 0-127 agg, 128-255 x (in-place).
// Wcat2 [128][256]: k<128 -> Wl[c][k], k>=128 -> Wr[c][k-128]. blockIdx.y = path.
__global__ __launch_bounds__(512) void gemmL(
    f16* __restrict__ axb, f16* __restrict__ axa, const f16* __restrict__ Wall,
    const float* __restrict__ bb, const float* __restrict__ ba, int lidx, int n) {
  __shared__ __align__(16) f16 As[2][4][256][8];  // 32 KB
  __shared__ __align__(16) f16 Bs[2][4][128][8];  // 16 KB
  const int path = blockIdx.y;
  f16* ax = path ? axa : axb;
  const f16* W = Wall + (size_t)(path * 2 + lidx) * 32768;
  const float* bias = (path ? ba : bb) + lidx * 128;

  const int tid = threadIdx.x;
  const int lane = tid & 63;
  const int wid = tid >> 6;
  const int wr = wid >> 1;  // 0..3
  const int wc = wid & 1;   // 0..1
  const int row0 = blockIdx.x * 256;

  const int bcol = tid & 127;
  const int bkb = tid >> 7;  // 0..3
  const int sArow = tid & 255;
  const int sAkb0 = tid >> 8;  // 0..1
  int arow = row0 + sArow;
  if (arow >= n) arow = n - 1;

  f32x4 acc[4][4];
#pragma unroll
  for (int m = 0; m < 4; ++m)
#pragma unroll
    for (int q = 0; q < 4; ++q) acc[m][q] = (f32x4)0.f;

  auto stage = [&](int buf, int k0) {
    gld_lds16(W + (size_t)bcol * 256 + k0 + bkb * 8, &Bs[buf][bkb][bcol][0]);
#pragma unroll
    for (int p = 0; p < 2; ++p) {
      int kb = sAkb0 + 2 * p;
      gld_lds16(ax + (size_t)arow * 256 + k0 + kb * 8, &As[buf][kb][sArow][0]);
    }
  };

  stage(0, 0);
  __syncthreads();
  int buf = 0;
  for (int t = 0; t < 8; ++t) {
    if (t + 1 < 8) stage(buf ^ 1, (t + 1) * 32);
    const int kb = lane >> 4;
    const int r16 = lane & 15;
    f16x8 a[4], b[4];
#pragma unroll
    for (int m = 0; m < 4; ++m)
      a[m] = *(const f16x8*)&As[buf][kb][wr * 64 + m * 16 + r16][0];
#pragma unroll
    for (int q = 0; q < 4; ++q)
      b[q] = *(const f16x8*)&Bs[buf][kb][wc * 64 + q * 16 + r16][0];
#pragma unroll
    for (int m = 0; m < 4; ++m)
#pragma unroll
      for (int q = 0; q < 4; ++q)
        acc[m][q] =
            __builtin_amdgcn_mfma_f32_16x16x32_f16(a[m], b[q], acc[m][q], 0, 0, 0);
    __syncthreads();
    buf ^= 1;
  }

  const int crow = (lane >> 4) * 4;
  const int ccol = lane & 15;
#pragma unroll
  for (int m = 0; m < 4; ++m) {
#pragma unroll
    for (int r = 0; r < 4; ++r) {
      int row = row0 + wr * 64 + m * 16 + crow + r;
      if (row < n) {
#pragma unroll
        for (int q = 0; q < 4; ++q) {
          int col = wc * 64 + q * 16 + ccol;
          float v = acc[m][q][r] + bias[col];
          ax[(size_t)row * 256 + 128 + col] = (f16)fmaxf(v, 0.0f);
        }
      }
    }
  }
}

// ---------------- weight conversion ----------------
__global__ void cvtW(const float* __restrict__ Wl, const float* __restrict__ Wr,
                     f16* __restrict__ outp, int K) {
  int c = blockIdx.y;
  int k = blockIdx.x * 256 + threadIdx.x;
  if (k < K)
    outp[(size_t)c * K + k] =
        (f16)((c < 128) ? Wl[(size_t)c * K + k] : Wr[(size_t)(c - 128) * K + k]);
}

// [4][128][256]: l = {b0,b1,a0,a1}; k<128 -> Wl, k>=128 -> Wr
__global__ void cvtW_small(const float* __restrict__ Wl_b, const float* __restrict__ Wr_b,
                           const float* __restrict__ Wl_a, const float* __restrict__ Wr_a,
                           f16* __restrict__ outp) {
  int idx = blockIdx.x * 256 + threadIdx.x;  // 4*128*256 = 131072
  int l = idx >> 15;
  int c = (idx >> 8) & 127;
  int k = idx & 255;
  const float* Wl = (l < 2) ? Wl_b + (size_t)l * 16384 : Wl_a + (size_t)(l - 2) * 16384;
  const float* Wr = (l < 2) ? Wr_b + (size_t)l * 16384 : Wr_a + (size_t)(l - 2) * 16384;
  float v = (k < 128) ? Wl[(size_t)c * 128 + k] : Wr[(size_t)c * 128 + (k - 128)];
  outp[idx] = (f16)v;
}

// ---------------- CSR build ----------------
__global__ void k_count(const int* __restrict__ nbr, int* __restrict__ deg) {
  int e = blockIdx.x * 256 + threadIdx.x;
  if (e < NEDGE) atomicAdd(&deg[nbr[e]], 1);
}
__global__ void k_scan1(const int* __restrict__ deg, int* __restrict__ rowptr,
                        int* __restrict__ bsum) {
  __shared__ int s[256];
  int t = threadIdx.x, i = blockIdx.x * 256 + t;
  int v = (i < N_ATOMS) ? deg[i] : 0;
  s[t] = v;
  __syncthreads();
  for (int off = 1; off < 256; off <<= 1) {
    int x = (t >= off) ? s[t - off] : 0;
    __syncthreads();
    s[t] += x;
    __syncthreads();
  }
  if (i < N_ATOMS) rowptr[i] = s[t] - v;
  if (t == 255) bsum[blockIdx.x] = s[255];
}
__global__ void k_scan2(int* __restrict__ bsum) {
  __shared__ int s[256];
  int t = threadIdx.x;
  int v = (t < NBLK) ? bsum[t] : 0;
  s[t] = v;
  __syncthreads();
  for (int off = 1; off < 256; off <<= 1) {
    int x = (t >= off) ? s[t - off] : 0;
    __syncthreads();
    s[t] += x;
    __syncthreads();
  }
  if (t < NBLK) bsum[t] = s[t] - v;
}
__global__ void k_scan3(int* __restrict__ rowptr, const int* __restrict__ bsum) {
  int i = blockIdx.x * 256 + threadIdx.x;
  if (i < N_ATOMS) rowptr[i] += bsum[blockIdx.x];
  if (i == 0) rowptr[N_ATOMS] = NEDGE;
}
__global__ void k_fill(const int* __restrict__ nbr, const int* __restrict__ rowptr,
                       int* __restrict__ cursor, int* __restrict__ eidx) {
  int e = blockIdx.x * 256 + threadIdx.x;
  if (e < NEDGE) {
    int dst = nbr[e];
    int pos = rowptr[dst] + atomicAdd(&cursor[dst], 1);
    eidx[pos] = e / NEIGH;
  }
}

// ---------------- layer-1 finalize: x = relu(mean_j P[src_j] + b + Q) ----------------
__global__ __launch_bounds__(256) void gather_fin1(
    const f16* __restrict__ Pb, const f16* __restrict__ Qb,
    const f16* __restrict__ Pa, const f16* __restrict__ Qa,
    const int* __restrict__ rowptr, const int* __restrict__ eidx,
    const float* __restrict__ bias_b, const float* __restrict__ bias_a,
    f16* __restrict__ axb, f16* __restrict__ axa) {
  const int path = blockIdx.y;
  const f16* P = path ? Pa : Pb;
  const f16* Q = path ? Qa : Qb;
  const float* bias = path ? bias_a : bias_b;
  f16* ax = path ? axa : axb;
  const int t = threadIdx.x;
  const int a = blockIdx.x * 16 + (t >> 4);
  const int g = (t & 15) * 8;
  const int s0 = rowptr[a], s1 = rowptr[a + 1];
  float acc[8];
#pragma unroll
  for (int u = 0; u < 8; ++u) acc[u] = 0.f;
  int j = s0;
  for (; j + 4 <= s1; j += 4) {
    int src0 = eidx[j], src1 = eidx[j + 1], src2 = eidx[j + 2], src3 = eidx[j + 3];
    f16x8 v0 = *(const f16x8*)&P[(size_t)src0 * 128 + g];
    f16x8 v1 = *(const f16x8*)&P[(size_t)src1 * 128 + g];
    f16x8 v2 = *(const f16x8*)&P[(size_t)src2 * 128 + g];
    f16x8 v3 = *(const f16x8*)&P[(size_t)src3 * 128 + g];
#pragma unroll
    for (int u = 0; u < 8; ++u)
      acc[u] += ((float)v0[u] + (float)v1[u]) + ((float)v2[u] + (float)v3[u]);
  }
  for (; j < s1; ++j) {
    f16x8 v = *(const f16x8*)&P[(size_t)eidx[j] * 128 + g];
#pragma unroll
    for (int u = 0; u < 8; ++u) acc[u] += (float)v[u];
  }
  f16x8 q = *(const f16x8*)&Q[(size_t)a * 128 + g];
  float inv = 1.0f / fmaxf((float)(s1 - s0), 1.0f);
  f16 outv[8];
#pragma unroll
  for (int u = 0; u < 8; ++u) {
    float v = acc[u] * inv + bias[g + u] + (float)q[u];
    outv[u] = (f16)fmaxf(v, 0.0f);
  }
  *(f16x8*)&ax[(size_t)a * 256 + 128 + g] = *(const f16x8*)outv;
}

// ---------------- layers 2-3 aggregation: agg half <- mean_j x[src_j] ----------------
__global__ __launch_bounds__(256) void gather_mean(
    f16* __restrict__ axb, f16* __restrict__ axa,
    const int* __restrict__ rowptr, const int* __restrict__ eidx) {
  f16* ax = blockIdx.y ? axa : axb;
  const int t = threadIdx.x;
  const int a = blockIdx.x * 16 + (t >> 4);
  const int g = (t & 15) * 8;
  const int s0 = rowptr[a], s1 = rowptr[a + 1];
  float acc[8];
#pragma unroll
  for (int u = 0; u < 8; ++u) acc[u] = 0.f;
  int j = s0;
  for (; j + 4 <= s1; j += 4) {
    int src0 = eidx[j], src1 = eidx[j + 1], src2 = eidx[j + 2], src3 = eidx[j + 3];
    f16x8 v0 = *(const f16x8*)&ax[(size_t)src0 * 256 + 128 + g];
    f16x8 v1 = *(const f16x8*)&ax[(size_t)src1 * 256 + 128 + g];
    f16x8 v2 = *(const f16x8*)&ax[(size_t)src2 * 256 + 128 + g];
    f16x8 v3 = *(const f16x8*)&ax[(size_t)src3 * 256 + 128 + g];
#pragma unroll
    for (int u = 0; u < 8; ++u)
      acc[u] += ((float)v0[u] + (float)v1[u]) + ((float)v2[u] + (float)v3[u]);
  }
  for (; j < s1; ++j) {
    f16x8 v = *(const f16x8*)&ax[(size_t)eidx[j] * 256 + 128 + g];
#pragma unroll
    for (int u = 0; u < 8; ++u) acc[u] += (float)v[u];
  }
  float inv = 1.0f / fmaxf((float)(s1 - s0), 1.0f);
  f16 outv[8];
#pragma unroll
  for (int u = 0; u < 8; ++u) outv[u] = (f16)(acc[u] * inv);
  *(f16x8*)&ax[(size_t)a * 256 + g] = *(const f16x8*)outv;
}

// ---------------- head: pool -> mlp -> mlp -> fc ----------------
__global__ __launch_bounds__(256) void head_kernel(
    const f16* __restrict__ axb, const f16* __restrict__ axa,
    const int* __restrict__ crys, const float* __restrict__ W_mlp,
    const float* __restrict__ b_mlp, const float* __restrict__ W_fc,
    const float* __restrict__ b_fc, float* __restrict__ outp) {
  __shared__ float sh0[256], sh1[256];
  const int cry = blockIdx.x, c = threadIdx.x;
  const int s = crys[2 * cry], e = crys[2 * cry + 1];
  const f16* src = (c < 128) ? axb : axa;
  const int ch = c & 127;
  float sum = 0.f;
  for (int r = s; r < e; ++r) sum += (float)src[(size_t)r * 256 + 128 + ch];
  sh0[c] = sum / fmaxf((float)(e - s), 1.0f);
  __syncthreads();
  {
    const float* wrow = W_mlp + (size_t)c * 256;
    float s2 = b_mlp[c];
#pragma unroll 8
    for (int k = 0; k < 256; k += 4) {
      float4 w = *(const float4*)&wrow[k];
      s2 += sh0[k] * w.x + sh0[k + 1] * w.y + sh0[k + 2] * w.z + sh0[k + 3] * w.w;
    }
    sh1[c] = s2;
  }
  __syncthreads();
  {
    const float* wrow = W_mlp + 65536 + (size_t)c * 256;
    float s2 = b_mlp[256 + c];
#pragma unroll 8
    for (int k = 0; k < 256; k += 4) {
      float4 w = *(const float4*)&wrow[k];
      s2 += sh1[k] * w.x + sh1[k + 1] * w.y + sh1[k + 2] * w.z + sh1[k + 3] * w.w;
    }
    sh0[c] = s2;
  }
  __syncthreads();
  if (c < 2) {
    const float* wrow = W_fc + c * 256;
    float s2 = b_fc[c];
    for (int k = 0; k < 256; ++k) s2 += sh0[k] * wrow[k];
    outp[cry * 2 + c] = s2;
  }
}

extern "C" void kernel_launch(void* const* d_in, const int* in_sizes, int n_in,
                              void* d_out, int out_size, void* d_ws, size_t ws_size,
                              hipStream_t stream) {
  const float* bond  = (const float*)d_in[0];
  const float* angle = (const float*)d_in[1];
  const int*   nbr   = (const int*)d_in[3];
  const int*   crys  = (const int*)d_in[4];
  const float* Wl_b1 = (const float*)d_in[5];
  const float* Wr_b1 = (const float*)d_in[6];
  const float* b_b1  = (const float*)d_in[7];
  const float* Wl_a1 = (const float*)d_in[8];
  const float* Wr_a1 = (const float*)d_in[9];
  const float* b_a1  = (const float*)d_in[10];
  const float* Wl_b  = (const float*)d_in[11];
  const float* Wr_b  = (const float*)d_in[12];
  const float* b_b   = (const float*)d_in[13];
  const float* Wl_a  = (const float*)d_in[14];
  const float* Wr_a  = (const float*)d_in[15];
  const float* b_a   = (const float*)d_in[16];
  const float* W_mlp = (const float*)d_in[17];
  const float* b_mlp = (const float*)d_in[18];
  const float* W_fc  = (const float*)d_in[19];
  const float* b_fc  = (const float*)d_in[20];

  char* w = (char*)d_ws;
  auto alloc = [&](size_t bytes) {
    void* p = (void*)w;
    w += (bytes + 255) & ~(size_t)255;
    return p;
  };
  f16* Pb   = (f16*)alloc((size_t)N_ATOMS * 128 * 2);
  f16* Qb   = (f16*)alloc((size_t)N_ATOMS * 128 * 2);
  f16* Pa   = (f16*)alloc((size_t)N_ATOMS * 128 * 2);
  f16* Qa   = (f16*)alloc((size_t)N_ATOMS * 128 * 2);
  f16* axb  = (f16*)alloc((size_t)N_ATOMS * 256 * 2);
  f16* axa  = (f16*)alloc((size_t)N_ATOMS * 256 * 2);
  f16* Wb1c = (f16*)alloc((size_t)256 * 480 * 2);
  f16* Wa1c = (f16*)alloc((size_t)256 * 1152 * 2);
  f16* Wsm  = (f16*)alloc((size_t)4 * 128 * 256 * 2);
  // deg+cursor as ONE contiguous block: the single memset must cover BOTH
  // (0xAA re-poison between timed replays otherwise leaves cursor garbage).
  int* deg    = (int*)alloc((size_t)2 * N_ATOMS * 4);
  int* cursor = deg + N_ATOMS;
  int* rowptr = (int*)alloc((size_t)(N_ATOMS + 1) * 4);
  int* eidx   = (int*)alloc((size_t)NEDGE * 4);
  int* bsum   = (int*)alloc(256 * 4);

  // weights -> fp16
  cvtW<<<dim3(2, 256), 256, 0, stream>>>(Wl_b1, Wr_b1, Wb1c, 480);
  cvtW<<<dim3(5, 256), 256, 0, stream>>>(Wl_a1, Wr_a1, Wa1c, 1152);
  cvtW_small<<<512, 256, 0, stream>>>(Wl_b, Wr_b, Wl_a, Wr_a, Wsm);

  // CSR build
  hipMemsetAsync(deg, 0, (size_t)2 * N_ATOMS * 4, stream);
  k_count<<<(NEDGE + 255) / 256, 256, 0, stream>>>(nbr, deg);
  k_scan1<<<NBLK, 256, 0, stream>>>(deg, rowptr, bsum);
  k_scan2<<<1, 256, 0, stream>>>(bsum);
  k_scan3<<<NBLK, 256, 0, stream>>>(rowptr, bsum);
  k_fill<<<(NEDGE + 255) / 256, 256, 0, stream>>>(nbr, rowptr, cursor, eidx);

  const int GT = (N_ATOMS + 255) / 256;  // 196 row-tiles
  const int AG = N_ATOMS / 16;           // 3125

  // layer 1 (project-then-aggregate; GBF fused into A staging; N-split over y)
  gemm1<2, 1152><<<dim3(GT, 2), 512, 0, stream>>>(angle, Wa1c, Pa, Qa, N_ATOMS);
  gemm1<1, 480><<<dim3(GT, 2), 512, 0, stream>>>(bond, Wb1c, Pb, Qb, N_ATOMS);
  gather_fin1<<<dim3(AG, 2), 256, 0, stream>>>(Pb, Qb, Pa, Qa, rowptr, eidx,
                                               b_b1, b_a1, axb, axa);

  // layers 2-3 (aggregate-then-project, both paths per launch)
  for (int l = 0; l < 2; ++l) {
    gather_mean<<<dim3(AG, 2), 256, 0, stream>>>(axb, axa, rowptr, eidx);
    gemmL<<<dim3(GT, 2), 512, 0, stream>>>(axb, axa, Wsm, b_b, b_a, l, N_ATOMS);
  }

  // head
  head_kernel<<<NCRYS, 256, 0, stream>>>(axb, axa, crys, W_mlp, b_mlp, W_fc, b_fc,
                                         (float*)d_out);
}